// Round 6
// baseline (214.153 us; speedup 1.0000x reference)
//
#include <hip/hip_runtime.h>
#include <math.h>

// BertBidafAttention B=16, CL=512, QL=64, H=768 — 3-launch pipeline (R4 skeleton):
//   K1 k_u_beta : u = q @ W (W split+transposed in LDS, loads software-pipelined),
//                 beta = q @ bias
//   K2 k_s_sm   : s = c @ u^T + beta (DB LDS c-split, u reg-prefetched),
//                 row softmax -> s1, per-tile column stats -> pstats (LSE partials),
//                 pre-masked transposed raw s -> sT[b][q][c] f32
//   K3 k_tfin3  : grid (12 h, 16 b x 2 half) = 384 blocks, LDS 31 KB (~2 blk/CU):
//                 A') merge 32 col-stat partials -> m[q], inv[q]
//                 B)  stage qT (LDS bf16)
//                 C)  t-slice = s2^T @ c, s2 computed INLINE as exp(sT-m)*inv
//                     (c transposed through DB LDS; no s2L buffer)
//                 D)  out = [c, a, c*a, c*bvec] over this half's 256 c-rows
// R5 post-mortem: cooperative launch never ran (zeros) -> reverted to 3 launches.
// This round attacks K3 occupancy (was 1 blk/CU, 94KB LDS, 192/256 CUs).

#define B_  16
#define CL_ 512
#define QL_ 64
#define H_  768
#define M_  (B_ * CL_)   // 8192

typedef __attribute__((ext_vector_type(8))) short s8v;   // 8 bf16
typedef __attribute__((ext_vector_type(4))) float f4v;   // MFMA acc

__device__ __forceinline__ unsigned short bf16_rne(float x) {
    unsigned int u = __float_as_uint(x);
    u += 0x7fffu + ((u >> 16) & 1u);
    return (unsigned short)(u >> 16);
}
__device__ __forceinline__ float bf16_f(unsigned short h) {
    return __uint_as_float((unsigned int)h << 16);
}
__device__ __forceinline__ void split2(float x, unsigned short& h, unsigned short& l) {
    h = bf16_rne(x);
    l = bf16_rne(x - bf16_f(h));
}

// ---------- K1: u = q @ W (split-bf16; W staged+transposed+split in LDS,
//                loads pipelined under MFMA) + beta blocks (blockIdx.x >= 192) ----------
__global__ __launch_bounds__(256) void k_u_beta(const float* __restrict__ q,
    const float* __restrict__ W, const float* __restrict__ bias,
    unsigned short* __restrict__ uh, unsigned short* __restrict__ ul,
    float* __restrict__ beta)
{
    if (blockIdx.x >= 192) {
        const int row = (blockIdx.x - 192) * 4 + (threadIdx.x >> 6);
        const int lane = threadIdx.x & 63;
        float p = 0.f;
        for (int d = lane; d < H_; d += 64) p = fmaf(bias[d], q[(size_t)row * H_ + d], p);
#pragma unroll
        for (int o = 32; o; o >>= 1) p += __shfl_xor(p, o);
        if (lane == 0) beta[row] = p;
        return;
    }
    __shared__ unsigned short Wh[64][40], Wl[64][40];
    const int m0 = (blockIdx.x & 15) * 64, n0 = (blockIdx.x >> 4) * 64;
    const int t = threadIdx.x, w = t >> 6, lane = t & 63;
    const int fm = lane & 15, quad = lane >> 4;
    const int mrow = m0 + w * 16 + fm;
    const int dd = t >> 3, hc = (t & 7) * 8;
    f4v acc[4];
#pragma unroll
    for (int j = 0; j < 4; ++j) acc[j] = (f4v){0.f, 0.f, 0.f, 0.f};
    // preload k0 = 0
    const float* wp0 = &W[(size_t)dd * H_ + n0 + hc];
    float4 v0 = *(const float4*)wp0, v1 = *(const float4*)(wp0 + 4);
    const float* ap0 = &q[(size_t)mrow * H_ + quad * 8];
    float4 a0 = *(const float4*)ap0, a1 = *(const float4*)(ap0 + 4);
    for (int k0 = 0; k0 < H_; k0 += 32) {
        const float as[8] = {a0.x, a0.y, a0.z, a0.w, a1.x, a1.y, a1.z, a1.w};
        s8v fah, fal;
#pragma unroll
        for (int j = 0; j < 8; ++j) { unsigned short h, l; split2(as[j], h, l); fah[j] = (short)h; fal[j] = (short)l; }
        const float ws_[8] = {v0.x, v0.y, v0.z, v0.w, v1.x, v1.y, v1.z, v1.w};
        __syncthreads();   // protect previous iteration's LDS reads
#pragma unroll
        for (int j = 0; j < 8; ++j) {
            unsigned short h, l; split2(ws_[j], h, l);
            Wh[hc + j][dd] = h; Wl[hc + j][dd] = l;
        }
        if (k0 + 32 < H_) {   // prefetch next tile while MFMA runs
            const float* wp = &W[(size_t)(k0 + 32 + dd) * H_ + n0 + hc];
            v0 = *(const float4*)wp; v1 = *(const float4*)(wp + 4);
            const float* ap = &q[(size_t)mrow * H_ + k0 + 32 + quad * 8];
            a0 = *(const float4*)ap; a1 = *(const float4*)(ap + 4);
        }
        __syncthreads();
#pragma unroll
        for (int tn = 0; tn < 4; ++tn) {
            const s8v bh = *(const s8v*)&Wh[tn * 16 + fm][quad * 8];
            const s8v bl = *(const s8v*)&Wl[tn * 16 + fm][quad * 8];
            acc[tn] = __builtin_amdgcn_mfma_f32_16x16x32_bf16(fah, bh, acc[tn], 0, 0, 0);
            acc[tn] = __builtin_amdgcn_mfma_f32_16x16x32_bf16(fah, bl, acc[tn], 0, 0, 0);
            acc[tn] = __builtin_amdgcn_mfma_f32_16x16x32_bf16(fal, bh, acc[tn], 0, 0, 0);
        }
    }
#pragma unroll
    for (int tn = 0; tn < 4; ++tn) {
        const int col = n0 + tn * 16 + fm;
#pragma unroll
        for (int r = 0; r < 4; ++r) {
            const int row = m0 + w * 16 + quad * 4 + r;
            unsigned short h, l; split2(acc[tn][r], h, l);
            uh[(size_t)row * H_ + col] = h;
            ul[(size_t)row * H_ + col] = l;
        }
    }
}

// ---------- K2: s = c @ u^T + beta (DB LDS, u reg-prefetch) + rowSM -> s1
//                + col-stat partials -> pstats + pre-masked sT ----------
__global__ __launch_bounds__(256) void k_s_sm(const float* __restrict__ c,
    const unsigned short* __restrict__ uh, const unsigned short* __restrict__ ul,
    const float* __restrict__ beta, const int* __restrict__ q_mask,
    const int* __restrict__ c_mask,
    float* __restrict__ sT, unsigned short* __restrict__ s1,
    float* __restrict__ pstats)
{
    __shared__ unsigned short chh[2][16][40], cll[2][16][40];
    __shared__ float sL[16][65];
    const int m0 = blockIdx.x * 16;
    const int batch = m0 >> 9;
    const int cloc = m0 & (CL_ - 1);
    const int t = threadIdx.x, w = t >> 6, lane = t & 63;
    const int fm = lane & 15, quad = lane >> 4;
    const int srow = t >> 4, skk = (t & 15) * 2;
    f4v acc = (f4v){0.f, 0.f, 0.f, 0.f};

    const size_t bo0 = (size_t)(batch * QL_ + w * 16 + fm) * H_ + quad * 8;
    s8v bh = *(const s8v*)&uh[bo0];
    s8v bl = *(const s8v*)&ul[bo0];

    float2 v = *(const float2*)&c[(size_t)(m0 + srow) * H_ + skk];
    int p = 0;
    for (int k0 = 0; k0 < H_; k0 += 32) {
        unsigned short h0s, l0s, h1s, l1s;
        split2(v.x, h0s, l0s); split2(v.y, h1s, l1s);
        *(ushort2*)&chh[p][srow][skk] = make_ushort2(h0s, h1s);
        *(ushort2*)&cll[p][srow][skk] = make_ushort2(l0s, l1s);
        __syncthreads();
        if (k0 + 32 < H_) v = *(const float2*)&c[(size_t)(m0 + srow) * H_ + k0 + 32 + skk];
        s8v nbh = bh, nbl = bl;
        if (k0 + 32 < H_) {
            nbh = *(const s8v*)&uh[bo0 + k0 + 32];
            nbl = *(const s8v*)&ul[bo0 + k0 + 32];
        }
        const s8v fah = *(const s8v*)&chh[p][fm][quad * 8];
        const s8v fal = *(const s8v*)&cll[p][fm][quad * 8];
        acc = __builtin_amdgcn_mfma_f32_16x16x32_bf16(fah, bh, acc, 0, 0, 0);
        acc = __builtin_amdgcn_mfma_f32_16x16x32_bf16(fah, bl, acc, 0, 0, 0);
        acc = __builtin_amdgcn_mfma_f32_16x16x32_bf16(fal, bh, acc, 0, 0, 0);
        bh = nbh; bl = nbl;
        p ^= 1;
    }
    // epilogue: fill sL tile
    {
        const int col = w * 16 + fm;
        const float bb = beta[batch * QL_ + col];
#pragma unroll
        for (int r = 0; r < 4; ++r) {
            const int lr = quad * 4 + r;
            sL[lr][col] = acc[r] + bb;
        }
    }
    __syncthreads();
    // row softmax over q (64 cols); wave w handles rows 4w..4w+3
    const bool qm = q_mask[batch * QL_ + lane] != 0;
#pragma unroll
    for (int rr = 0; rr < 4; ++rr) {
        const int lr = w * 4 + rr;
        const float x = qm ? sL[lr][lane] : -1e30f;
        float mx = x;
#pragma unroll
        for (int o = 32; o; o >>= 1) mx = fmaxf(mx, __shfl_xor(mx, o));
        const float e = __expf(x - mx);
        float sm = e;
#pragma unroll
        for (int o = 32; o; o >>= 1) sm += __shfl_xor(sm, o);
        s1[(size_t)(m0 + lr) * QL_ + lane] = bf16_rne(e / sm);
    }
    // per-tile column stats (LSE partials), wave 0: lane = q column
    if (w == 0) {
        float xs[16];
        float pm = -1e30f;
#pragma unroll
        for (int r = 0; r < 16; ++r) {
            const float xv = c_mask[batch * CL_ + cloc + r] ? sL[r][lane] : -1e30f;
            xs[r] = xv; pm = fmaxf(pm, xv);
        }
        float ps = 0.f;
#pragma unroll
        for (int r = 0; r < 16; ++r) ps += __expf(xs[r] - pm);
        const int tile = cloc >> 4;   // 0..31
        *(float2*)&pstats[((size_t)(batch * 32 + tile) * 64 + lane) * 2] = make_float2(pm, ps);
    }
    // transposed PRE-MASKED raw-s write: sT[b][q][cloc..cloc+15]
    {
        const int qq = t >> 2, c4o = (t & 3) * 4;
        const int cb = batch * CL_ + cloc + c4o;
        float4 ov;
        ov.x = c_mask[cb + 0] ? sL[c4o + 0][qq] : -1e30f;
        ov.y = c_mask[cb + 1] ? sL[c4o + 1][qq] : -1e30f;
        ov.z = c_mask[cb + 2] ? sL[c4o + 2][qq] : -1e30f;
        ov.w = c_mask[cb + 3] ? sL[c4o + 3][qq] : -1e30f;
        *(float4*)&sT[((size_t)batch * QL_ + qq) * CL_ + cloc + c4o] = ov;
    }
}

// ---------- K3: stats-merge + t + finalize; grid (12, 32): b = y>>1, half = y&1 ----------
__global__ __launch_bounds__(256) void k_tfin3(const float* __restrict__ sT,
    const float* __restrict__ pstats,
    const unsigned short* __restrict__ s1, const float* __restrict__ q,
    const float* __restrict__ c, float* __restrict__ out)
{
    __shared__ unsigned short qT[64][72];      // q^T bf16 (h x q)   9216 B
    __shared__ unsigned short tT[64][72];      // t   bf16 (h x q)   9216 B
    __shared__ unsigned short Bs[2][64][40];   // c^T staging tile  10240 B
    __shared__ float sredm[4][64], sreds[4][64];                 //  2048 B
    __shared__ float statsM[64], statsI[64];                     //   512 B
    const int h0   = blockIdx.x * 64;
    const int b    = blockIdx.y >> 1;
    const int half = blockIdx.y & 1;
    const int t = threadIdx.x, w = t >> 6, lane = t & 63;
    const int fm = lane & 15, quad = lane >> 4;

    // ---- A': merge 32 column-softmax partials -> m[q], inv[q] ----
    {
        float2 pp[8];
        const float* pb = pstats + (size_t)b * 32 * 64 * 2;
#pragma unroll
        for (int i = 0; i < 8; ++i)
            pp[i] = *(const float2*)&pb[((size_t)(w * 8 + i) * 64 + lane) * 2];
        float m = pp[0].x;
#pragma unroll
        for (int i = 1; i < 8; ++i) m = fmaxf(m, pp[i].x);
        sredm[w][lane] = m;
        __syncthreads();
        m = fmaxf(fmaxf(sredm[0][lane], sredm[1][lane]),
                  fmaxf(sredm[2][lane], sredm[3][lane]));
        float ss = 0.f;
#pragma unroll
        for (int i = 0; i < 8; ++i) ss += pp[i].y * __expf(pp[i].x - m);
        sreds[w][lane] = ss;
        __syncthreads();
        if (w == 0) {
            const float sum = sreds[0][lane] + sreds[1][lane] + sreds[2][lane] + sreds[3][lane];
            statsM[lane] = m;
            statsI[lane] = 1.f / sum;
        }
    }

    // ---- B: stage q^T ----
    {
        const int r = t >> 4, c4 = (t & 15) * 4;
#pragma unroll
        for (int i = 0; i < 4; ++i) {
            const int qr = r + 16 * i;
            const float4 v = *(const float4*)&q[((size_t)b * QL_ + qr) * H_ + h0 + c4];
            qT[c4 + 0][qr] = bf16_rne(v.x);
            qT[c4 + 1][qr] = bf16_rne(v.y);
            qT[c4 + 2][qr] = bf16_rne(v.z);
            qT[c4 + 3][qr] = bf16_rne(v.w);
        }
    }
    __syncthreads();   // stats + qT visible

    // hoist per-fragment-row m/inv
    float qm_[4], qi_[4];
#pragma unroll
    for (int tm = 0; tm < 4; ++tm) {
        qm_[tm] = statsM[tm * 16 + fm];
        qi_[tm] = statsI[tm * 16 + fm];
    }

    // ---- C: t-slice = (s2^T @ c), s2 inline = exp(sT - m)*inv (DB LDS c-transpose) ----
    {
        const int dd = t >> 3, hc = (t & 7) * 8;
        f4v acc[4];
#pragma unroll
        for (int j = 0; j < 4; ++j) acc[j] = (f4v){0.f, 0.f, 0.f, 0.f};
        const float* cp0 = &c[((size_t)b * CL_ + dd) * H_ + h0 + hc];
        float4 v0 = *(const float4*)cp0, v1 = *(const float4*)(cp0 + 4);
        const float* sp[4];
#pragma unroll
        for (int tm = 0; tm < 4; ++tm)
            sp[tm] = &sT[((size_t)b * QL_ + tm * 16 + fm) * CL_ + quad * 8];
        int p = 0;
        for (int d0 = 0; d0 < CL_; d0 += 32) {
            // issue sT loads for this step early
            float4 s0[4], s1r[4];
#pragma unroll
            for (int tm = 0; tm < 4; ++tm) {
                s0[tm]  = *(const float4*)(sp[tm] + d0);
                s1r[tm] = *(const float4*)(sp[tm] + d0 + 4);
            }
            const float xs[8] = {v0.x, v0.y, v0.z, v0.w, v1.x, v1.y, v1.z, v1.w};
#pragma unroll
            for (int j = 0; j < 8; ++j) Bs[p][hc + j][dd] = bf16_rne(xs[j]);
            __syncthreads();
            if (d0 + 32 < CL_) {
                const float* cp = &c[((size_t)b * CL_ + d0 + 32 + dd) * H_ + h0 + hc];
                v0 = *(const float4*)cp; v1 = *(const float4*)(cp + 4);
            }
            const s8v fb = *(const s8v*)&Bs[p][w * 16 + fm][quad * 8];
#pragma unroll
            for (int tm = 0; tm < 4; ++tm) {
                const float ex[8] = {s0[tm].x, s0[tm].y, s0[tm].z, s0[tm].w,
                                     s1r[tm].x, s1r[tm].y, s1r[tm].z, s1r[tm].w};
                s8v fa;
#pragma unroll
                for (int j = 0; j < 8; ++j)
                    fa[j] = (short)bf16_rne(__expf(ex[j] - qm_[tm]) * qi_[tm]);
                acc[tm] = __builtin_amdgcn_mfma_f32_16x16x32_bf16(fa, fb, acc[tm], 0, 0, 0);
            }
            p ^= 1;
        }
#pragma unroll
        for (int tm = 0; tm < 4; ++tm)
#pragma unroll
            for (int r = 0; r < 4; ++r)
                tT[w * 16 + fm][tm * 16 + quad * 4 + r] = bf16_rne(acc[tm][r]);
    }
    __syncthreads();

    // ---- D: finalize this half's 256 c-rows ----
    {
        const int cbase = half * 256 + w * 64;
        f4v aa[4][4], bb[4][4];
#pragma unroll
        for (int i = 0; i < 4; ++i)
#pragma unroll
            for (int j = 0; j < 4; ++j) { aa[i][j] = (f4v){0.f, 0.f, 0.f, 0.f}; bb[i][j] = aa[i][j]; }
#pragma unroll
        for (int ks = 0; ks < 2; ++ks) {
            s8v fa[4], fq[4], ft[4];
#pragma unroll
            for (int tm = 0; tm < 4; ++tm)
                fa[tm] = *(const s8v*)&s1[(size_t)(b * CL_ + cbase + tm * 16 + fm) * QL_ + ks * 32 + quad * 8];
#pragma unroll
            for (int tn = 0; tn < 4; ++tn) {
                fq[tn] = *(const s8v*)&qT[tn * 16 + fm][ks * 32 + quad * 8];
                ft[tn] = *(const s8v*)&tT[tn * 16 + fm][ks * 32 + quad * 8];
            }
#pragma unroll
            for (int tm = 0; tm < 4; ++tm)
#pragma unroll
                for (int tn = 0; tn < 4; ++tn) {
                    aa[tm][tn] = __builtin_amdgcn_mfma_f32_16x16x32_bf16(fa[tm], fq[tn], aa[tm][tn], 0, 0, 0);
                    bb[tm][tn] = __builtin_amdgcn_mfma_f32_16x16x32_bf16(fa[tm], ft[tn], bb[tm][tn], 0, 0, 0);
                }
        }
#pragma unroll
        for (int tm = 0; tm < 4; ++tm)
#pragma unroll
            for (int tn = 0; tn < 4; ++tn) {
                const int h = h0 + tn * 16 + fm;
#pragma unroll
                for (int r = 0; r < 4; ++r) {
                    const int crow = cbase + tm * 16 + quad * 4 + r;
                    const float cv = c[((size_t)b * CL_ + crow) * H_ + h];
                    const float av = aa[tm][tn][r], bv = bb[tm][tn][r];
                    float* ob = out + (size_t)(b * CL_ + crow) * (4 * H_);
                    ob[h]           = cv;
                    ob[H_ + h]      = av;
                    ob[2 * H_ + h]  = cv * av;
                    ob[3 * H_ + h]  = cv * bv;
                }
            }
    }
}

extern "C" void kernel_launch(void* const* d_in, const int* in_sizes, int n_in,
                              void* d_out, int out_size, void* d_ws, size_t ws_size,
                              hipStream_t stream) {
    const float* c      = (const float*)d_in[0];
    const float* q      = (const float*)d_in[1];
    const int*   c_mask = (const int*)d_in[2];
    const int*   q_mask = (const int*)d_in[3];
    const float* W      = (const float*)d_in[4];
    const float* bias   = (const float*)d_in[5];
    float* out = (float*)d_out;

    // workspace — total 6557696 B (~6.3 MB)
    char* base = (char*)d_ws;
    unsigned short* uh     = (unsigned short*)(base);               // 1572864
    unsigned short* ul     = (unsigned short*)(base + 1572864);     // 1572864
    float*          beta   = (float*)(base + 3145728);              // 4096
    float*          sT     = (float*)(base + 3149824);              // 2097152 (f32 [16][64][512])
    unsigned short* s1     = (unsigned short*)(base + 5246976);     // 1048576
    float*          pstats = (float*)(base + 6295552);              // 262144  (f32x2 [16][32][64])

    dim3 blk(256);
    k_u_beta <<<dim3(192 + 256),  blk, 0, stream>>>(q, W, bias, uh, ul, beta);
    k_s_sm   <<<dim3(512),        blk, 0, stream>>>(c, uh, ul, beta, q_mask, c_mask, sT, s1, pstats);
    k_tfin3  <<<dim3(12, 32),     blk, 0, stream>>>(sT, pstats, s1, q, c, out);
}

// Round 7
// 197.312 us; speedup vs baseline: 1.0854x; 1.0854x over previous
//
#include <hip/hip_runtime.h>
#include <math.h>

// BertBidafAttention B=16, CL=512, QL=64, H=768 — 3-launch pipeline.
// K1/K2: exactly the verified R4 versions (207.5 us). K3 only change this round:
//   512 threads (8 waves) instead of 256: phase C splits K across 2 wave-groups
//   (own DB staging tiles, partial-acc merge via LDS), phases A/D use all 8 waves.
//   Same total work as R4 (no duplication, no in-loop exp — R6's mistake).
//   LDS ~102 KB -> 1 blk/CU but 8 waves/CU (2/SIMD), 2x R4's TLP.

#define B_  16
#define CL_ 512
#define QL_ 64
#define H_  768
#define M_  (B_ * CL_)   // 8192

typedef __attribute__((ext_vector_type(8))) short s8v;   // 8 bf16
typedef __attribute__((ext_vector_type(4))) float f4v;   // MFMA acc

__device__ __forceinline__ unsigned short bf16_rne(float x) {
    unsigned int u = __float_as_uint(x);
    u += 0x7fffu + ((u >> 16) & 1u);
    return (unsigned short)(u >> 16);
}
__device__ __forceinline__ float bf16_f(unsigned short h) {
    return __uint_as_float((unsigned int)h << 16);
}
__device__ __forceinline__ void split2(float x, unsigned short& h, unsigned short& l) {
    h = bf16_rne(x);
    l = bf16_rne(x - bf16_f(h));
}

// ---------- K1: u = q @ W (split-bf16; W staged+transposed+split in LDS)
//                + beta blocks (blockIdx.x >= 192) ----------
__global__ __launch_bounds__(256) void k_u_beta(const float* __restrict__ q,
    const float* __restrict__ W, const float* __restrict__ bias,
    unsigned short* __restrict__ uh, unsigned short* __restrict__ ul,
    float* __restrict__ beta)
{
    if (blockIdx.x >= 192) {
        const int row = (blockIdx.x - 192) * 4 + (threadIdx.x >> 6);
        const int lane = threadIdx.x & 63;
        float p = 0.f;
        for (int d = lane; d < H_; d += 64) p = fmaf(bias[d], q[(size_t)row * H_ + d], p);
#pragma unroll
        for (int o = 32; o; o >>= 1) p += __shfl_xor(p, o);
        if (lane == 0) beta[row] = p;
        return;
    }
    __shared__ unsigned short Wh[64][40], Wl[64][40];
    const int m0 = (blockIdx.x & 15) * 64, n0 = (blockIdx.x >> 4) * 64;
    const int t = threadIdx.x, w = t >> 6, lane = t & 63;
    const int fm = lane & 15, quad = lane >> 4;
    const int mrow = m0 + w * 16 + fm;
    const int dd = t >> 3, hc = (t & 7) * 8;
    f4v acc[4];
#pragma unroll
    for (int j = 0; j < 4; ++j) acc[j] = (f4v){0.f, 0.f, 0.f, 0.f};
    for (int k0 = 0; k0 < H_; k0 += 32) {
        const float* wp = &W[(size_t)(k0 + dd) * H_ + n0 + hc];
        const float4 v0 = *(const float4*)wp, v1 = *(const float4*)(wp + 4);
        const float* ap = &q[(size_t)mrow * H_ + k0 + quad * 8];
        const float4 a0 = *(const float4*)ap, a1 = *(const float4*)(ap + 4);
        const float as[8] = {a0.x, a0.y, a0.z, a0.w, a1.x, a1.y, a1.z, a1.w};
        s8v fah, fal;
#pragma unroll
        for (int j = 0; j < 8; ++j) { unsigned short h, l; split2(as[j], h, l); fah[j] = (short)h; fal[j] = (short)l; }
        const float ws[8] = {v0.x, v0.y, v0.z, v0.w, v1.x, v1.y, v1.z, v1.w};
        __syncthreads();   // protect previous iteration's LDS reads
#pragma unroll
        for (int j = 0; j < 8; ++j) {
            unsigned short h, l; split2(ws[j], h, l);
            Wh[hc + j][dd] = h; Wl[hc + j][dd] = l;
        }
        __syncthreads();
#pragma unroll
        for (int tn = 0; tn < 4; ++tn) {
            const s8v bh = *(const s8v*)&Wh[tn * 16 + fm][quad * 8];
            const s8v bl = *(const s8v*)&Wl[tn * 16 + fm][quad * 8];
            acc[tn] = __builtin_amdgcn_mfma_f32_16x16x32_bf16(fah, bh, acc[tn], 0, 0, 0);
            acc[tn] = __builtin_amdgcn_mfma_f32_16x16x32_bf16(fah, bl, acc[tn], 0, 0, 0);
            acc[tn] = __builtin_amdgcn_mfma_f32_16x16x32_bf16(fal, bh, acc[tn], 0, 0, 0);
        }
    }
#pragma unroll
    for (int tn = 0; tn < 4; ++tn) {
        const int col = n0 + tn * 16 + fm;
#pragma unroll
        for (int r = 0; r < 4; ++r) {
            const int row = m0 + w * 16 + quad * 4 + r;
            unsigned short h, l; split2(acc[tn][r], h, l);
            uh[(size_t)row * H_ + col] = h;
            ul[(size_t)row * H_ + col] = l;
        }
    }
}

// ---------- K2: s = c @ u^T + beta (c split once -> DB LDS) + row softmax -> s1
//                epilogue writes sT[b][q][c] (f32, transposed via sL) ----------
__global__ __launch_bounds__(256) void k_s_sm(const float* __restrict__ c,
    const unsigned short* __restrict__ uh, const unsigned short* __restrict__ ul,
    const float* __restrict__ beta, const int* __restrict__ q_mask,
    float* __restrict__ sT, unsigned short* __restrict__ s1)
{
    __shared__ unsigned short chh[2][16][40], cll[2][16][40];
    __shared__ float sL[16][65];
    const int m0 = blockIdx.x * 16;
    const int batch = m0 >> 9;
    const int cloc = m0 & (CL_ - 1);
    const int t = threadIdx.x, w = t >> 6, lane = t & 63;
    const int fm = lane & 15, quad = lane >> 4;
    const int srow = t >> 4, skk = (t & 15) * 2;   // staging: 16 rows x 32 k, 2 elems/thread
    f4v acc = (f4v){0.f, 0.f, 0.f, 0.f};

    float2 v = *(const float2*)&c[(size_t)(m0 + srow) * H_ + skk];
    int p = 0;
    for (int k0 = 0; k0 < H_; k0 += 32) {
        unsigned short h0s, l0s, h1s, l1s;
        split2(v.x, h0s, l0s); split2(v.y, h1s, l1s);
        *(ushort2*)&chh[p][srow][skk] = make_ushort2(h0s, h1s);
        *(ushort2*)&cll[p][srow][skk] = make_ushort2(l0s, l1s);
        __syncthreads();
        if (k0 + 32 < H_) v = *(const float2*)&c[(size_t)(m0 + srow) * H_ + k0 + 32 + skk];
        const s8v fah = *(const s8v*)&chh[p][fm][quad * 8];
        const s8v fal = *(const s8v*)&cll[p][fm][quad * 8];
        const size_t bo = (size_t)(batch * QL_ + w * 16 + fm) * H_ + k0 + quad * 8;
        const s8v bh = *(const s8v*)&uh[bo];
        const s8v bl = *(const s8v*)&ul[bo];
        acc = __builtin_amdgcn_mfma_f32_16x16x32_bf16(fah, bh, acc, 0, 0, 0);
        acc = __builtin_amdgcn_mfma_f32_16x16x32_bf16(fah, bl, acc, 0, 0, 0);
        acc = __builtin_amdgcn_mfma_f32_16x16x32_bf16(fal, bh, acc, 0, 0, 0);
        p ^= 1;
    }
    // epilogue: fill sL tile
    {
        const int col = w * 16 + fm;
        const float bb = beta[batch * QL_ + col];
#pragma unroll
        for (int r = 0; r < 4; ++r) {
            const int lr = quad * 4 + r;
            sL[lr][col] = acc[r] + bb;
        }
    }
    __syncthreads();
    // row softmax over q (64 cols); wave w handles rows 4w..4w+3
    const bool qm = q_mask[batch * QL_ + lane] != 0;
#pragma unroll
    for (int rr = 0; rr < 4; ++rr) {
        const int lr = w * 4 + rr;
        const float x = qm ? sL[lr][lane] : -1e30f;
        float mx = x;
#pragma unroll
        for (int o = 32; o; o >>= 1) mx = fmaxf(mx, __shfl_xor(mx, o));
        const float e = __expf(x - mx);
        float sm = e;
#pragma unroll
        for (int o = 32; o; o >>= 1) sm += __shfl_xor(sm, o);
        s1[(size_t)(m0 + lr) * QL_ + lane] = bf16_rne(e / sm);
    }
    // transposed raw-s write: sT[b][q][cloc..cloc+15]
    {
        const int qq = t >> 2, c4o = (t & 3) * 4;
        float4 ov;
        ov.x = sL[c4o + 0][qq];
        ov.y = sL[c4o + 1][qq];
        ov.z = sL[c4o + 2][qq];
        ov.w = sL[c4o + 3][qq];
        *(float4*)&sT[((size_t)batch * QL_ + qq) * CL_ + cloc + c4o] = ov;
    }
}

// ---------- K3: fused colSM + t + finalize, 512 threads (8 waves), one block per (h0, b).
//   A) colSM from sT -> s2L (LDS bf16, XOR-swz), 8 q-rows per wave
//   B) stage qT
//   C) t-slice = s2^T @ c, K split across 2 wave-groups (own DB c-tiles),
//      partial accs merged via LDS
//   D) finalize all 512 c-rows, one 64-row chunk per wave ----------
__global__ __launch_bounds__(512) void k_tfin3(const float* __restrict__ sT,
    const unsigned short* __restrict__ s1, const float* __restrict__ q,
    const float* __restrict__ c, const int* __restrict__ c_mask,
    float* __restrict__ out)
{
    __shared__ unsigned short s2L[64 * 512];      // colSM result, XOR-swizzled (65536 B)
    __shared__ unsigned short Bs[2][2][64][40];   // c^T staging, [grp][dbuf]   (20480 B)
    __shared__ unsigned short qT[64][72];         // q^T bf16 (h x q)            (9216 B)
    __shared__ unsigned short tT[64][72];         // t   bf16 (h x q)            (9216 B)
    const int h0 = blockIdx.x * 64;
    const int b  = blockIdx.y;
    const int t = threadIdx.x, w = t >> 6, lane = t & 63;
    const int fm = lane & 15, quad = lane >> 4;
    const int grp = w >> 2;        // K-half: 0 -> d0 in [0,256), 1 -> [256,512)
    const int wl  = w & 3;         // h-partition within group (wl*16 .. wl*16+15)

    // ---- phase A: column softmax (over c) for batch b -> s2L (8 q-rows/wave) ----
    {
        const int cbase8 = lane * 8;
        int cm8[8];
#pragma unroll
        for (int j = 0; j < 8; ++j) cm8[j] = c_mask[b * CL_ + cbase8 + j];
        const float* stb = sT + (size_t)b * QL_ * CL_;
#pragma unroll
        for (int qi = 0; qi < 8; ++qi) {
            const int qq = w * 8 + qi;
            const float* sr = stb + (size_t)qq * CL_ + cbase8;
            const float4 v0 = *(const float4*)sr, v1 = *(const float4*)(sr + 4);
            float x[8] = {v0.x, v0.y, v0.z, v0.w, v1.x, v1.y, v1.z, v1.w};
#pragma unroll
            for (int j = 0; j < 8; ++j) x[j] = cm8[j] ? x[j] : -1e30f;
            float m = x[0];
#pragma unroll
            for (int j = 1; j < 8; ++j) m = fmaxf(m, x[j]);
#pragma unroll
            for (int o = 32; o; o >>= 1) m = fmaxf(m, __shfl_xor(m, o));
            float e[8], sm = 0.f;
#pragma unroll
            for (int j = 0; j < 8; ++j) { e[j] = __expf(x[j] - m); sm += e[j]; }
#pragma unroll
            for (int o = 32; o; o >>= 1) sm += __shfl_xor(sm, o);
            const float inv = 1.f / sm;
            s8v sv;
#pragma unroll
            for (int j = 0; j < 8; ++j) sv[j] = (short)bf16_rne(e[j] * inv);
            const int boff = ((qq * 512 + cbase8) * 2) ^ ((qq & 7) << 4);
            *(s8v*)((char*)s2L + boff) = sv;
        }
    }

    // ---- phase B: stage q^T (512 threads, 2 rows each) ----
    {
        const int r = t >> 4, c4 = (t & 15) * 4;
#pragma unroll
        for (int i = 0; i < 2; ++i) {
            const int qr = r + 32 * i;
            const float4 v = *(const float4*)&q[((size_t)b * QL_ + qr) * H_ + h0 + c4];
            qT[c4 + 0][qr] = bf16_rne(v.x);
            qT[c4 + 1][qr] = bf16_rne(v.y);
            qT[c4 + 2][qr] = bf16_rne(v.z);
            qT[c4 + 3][qr] = bf16_rne(v.w);
        }
    }

    // ---- phase C: t-slice = (s2^T @ c), K split across wave-groups ----
    f4v acc[4];
#pragma unroll
    for (int j = 0; j < 4; ++j) acc[j] = (f4v){0.f, 0.f, 0.f, 0.f};
    {
        const int tl = t & 255;                 // thread id within group
        const int dd = tl >> 3, hc = (tl & 7) * 8;
        const int gbase = grp * 256;            // this group's K offset
        const float* cp0 = &c[((size_t)b * CL_ + gbase + dd) * H_ + h0 + hc];
        float4 v0 = *(const float4*)cp0, v1 = *(const float4*)(cp0 + 4);
        int p = 0;
        for (int d0 = 0; d0 < 256; d0 += 32) {
            const float xs[8] = {v0.x, v0.y, v0.z, v0.w, v1.x, v1.y, v1.z, v1.w};
#pragma unroll
            for (int j = 0; j < 8; ++j) Bs[grp][p][hc + j][dd] = bf16_rne(xs[j]);
            __syncthreads();   // first iteration also orders phase-A/B LDS writes
            if (d0 + 32 < 256) {
                const float* cp = &c[((size_t)b * CL_ + gbase + d0 + 32 + dd) * H_ + h0 + hc];
                v0 = *(const float4*)cp; v1 = *(const float4*)(cp + 4);
            }
            const s8v fb = *(const s8v*)&Bs[grp][p][wl * 16 + fm][quad * 8];
#pragma unroll
            for (int tm = 0; tm < 4; ++tm) {
                const int boff = (((tm * 16 + fm) * 512 + gbase + d0 + quad * 8) * 2) ^ ((fm & 7) << 4);
                const s8v fa = *(const s8v*)((const char*)s2L + boff);
                acc[tm] = __builtin_amdgcn_mfma_f32_16x16x32_bf16(fa, fb, acc[tm], 0, 0, 0);
            }
            p ^= 1;
        }
    }
    __syncthreads();   // all s2L/Bs reads done before reusing s2L as dump area
    // merge group partials: grp1 dumps f32 accs into (dead) s2L, grp0 sums -> tT
    {
        float* dumpf = (float*)s2L;   // needs 16 KB of the 64 KB region
        if (grp == 1) {
#pragma unroll
            for (int tm = 0; tm < 4; ++tm)
#pragma unroll
                for (int r = 0; r < 4; ++r)
                    dumpf[((wl * 4 + tm) * 4 + r) * 64 + lane] = acc[tm][r];
        }
        __syncthreads();
        if (grp == 0) {
#pragma unroll
            for (int tm = 0; tm < 4; ++tm)
#pragma unroll
                for (int r = 0; r < 4; ++r)
                    tT[wl * 16 + fm][tm * 16 + quad * 4 + r] =
                        bf16_rne(acc[tm][r] + dumpf[((wl * 4 + tm) * 4 + r) * 64 + lane]);
        }
    }
    __syncthreads();

    // ---- phase D: finalize all 512 c-rows, one 64-row chunk per wave ----
    {
        const int cbase = w * 64;
        f4v aa[4][4], bb[4][4];
#pragma unroll
        for (int i = 0; i < 4; ++i)
#pragma unroll
            for (int j = 0; j < 4; ++j) { aa[i][j] = (f4v){0.f, 0.f, 0.f, 0.f}; bb[i][j] = aa[i][j]; }
#pragma unroll
        for (int ks = 0; ks < 2; ++ks) {
            s8v fa[4], fq[4], ft[4];
#pragma unroll
            for (int tm = 0; tm < 4; ++tm)
                fa[tm] = *(const s8v*)&s1[(size_t)(b * CL_ + cbase + tm * 16 + fm) * QL_ + ks * 32 + quad * 8];
#pragma unroll
            for (int tn = 0; tn < 4; ++tn) {
                fq[tn] = *(const s8v*)&qT[tn * 16 + fm][ks * 32 + quad * 8];
                ft[tn] = *(const s8v*)&tT[tn * 16 + fm][ks * 32 + quad * 8];
            }
#pragma unroll
            for (int tm = 0; tm < 4; ++tm)
#pragma unroll
                for (int tn = 0; tn < 4; ++tn) {
                    aa[tm][tn] = __builtin_amdgcn_mfma_f32_16x16x32_bf16(fa[tm], fq[tn], aa[tm][tn], 0, 0, 0);
                    bb[tm][tn] = __builtin_amdgcn_mfma_f32_16x16x32_bf16(fa[tm], ft[tn], bb[tm][tn], 0, 0, 0);
                }
        }
#pragma unroll
        for (int tm = 0; tm < 4; ++tm)
#pragma unroll
            for (int tn = 0; tn < 4; ++tn) {
                const int h = h0 + tn * 16 + fm;
#pragma unroll
                for (int r = 0; r < 4; ++r) {
                    const int crow = cbase + tm * 16 + quad * 4 + r;
                    const float cv = c[((size_t)b * CL_ + crow) * H_ + h];
                    const float av = aa[tm][tn][r], bv = bb[tm][tn][r];
                    float* ob = out + (size_t)(b * CL_ + crow) * (4 * H_);
                    ob[h]           = cv;
                    ob[H_ + h]      = av;
                    ob[2 * H_ + h]  = cv * av;
                    ob[3 * H_ + h]  = cv * bv;
                }
            }
    }
}

extern "C" void kernel_launch(void* const* d_in, const int* in_sizes, int n_in,
                              void* d_out, int out_size, void* d_ws, size_t ws_size,
                              hipStream_t stream) {
    const float* c      = (const float*)d_in[0];
    const float* q      = (const float*)d_in[1];
    const int*   c_mask = (const int*)d_in[2];
    const int*   q_mask = (const int*)d_in[3];
    const float* W      = (const float*)d_in[4];
    const float* bias   = (const float*)d_in[5];
    float* out = (float*)d_out;

    // workspace — total 6295552 B (~6.0 MB)
    char* base = (char*)d_ws;
    unsigned short* uh   = (unsigned short*)(base);               // 1572864
    unsigned short* ul   = (unsigned short*)(base + 1572864);     // 1572864
    float*          beta = (float*)(base + 3145728);              // 4096
    float*          sT   = (float*)(base + 3149824);              // 2097152 (f32 [16][64][512])
    unsigned short* s1   = (unsigned short*)(base + 5246976);     // 1048576

    k_u_beta <<<dim3(192 + 256), dim3(256), 0, stream>>>(q, W, bias, uh, ul, beta);
    k_s_sm   <<<dim3(512),       dim3(256), 0, stream>>>(c, uh, ul, beta, q_mask, sT, s1);
    k_tfin3  <<<dim3(12, 16),    dim3(512), 0, stream>>>(sT, s1, q, c, c_mask, out);
}

// Round 9
// 193.085 us; speedup vs baseline: 1.1091x; 1.0219x over previous
//
#include <hip/hip_runtime.h>
#include <math.h>

// BertBidafAttention B=16, CL=512, QL=64, H=768 — 3-launch pipeline.
// K1/K3: exactly the verified R7 versions (197.3 us). K2 (32-row/512-thread/BK=64)
// resubmitted unchanged from R8: audit found no fault (bounds/races/alignment all
// verified); R8's "container failed twice" attributed to infra flake (cf. R2->R3).

#define B_  16
#define CL_ 512
#define QL_ 64
#define H_  768
#define M_  (B_ * CL_)   // 8192

typedef __attribute__((ext_vector_type(8))) short s8v;   // 8 bf16
typedef __attribute__((ext_vector_type(4))) float f4v;   // MFMA acc

__device__ __forceinline__ unsigned short bf16_rne(float x) {
    unsigned int u = __float_as_uint(x);
    u += 0x7fffu + ((u >> 16) & 1u);
    return (unsigned short)(u >> 16);
}
__device__ __forceinline__ float bf16_f(unsigned short h) {
    return __uint_as_float((unsigned int)h << 16);
}
__device__ __forceinline__ void split2(float x, unsigned short& h, unsigned short& l) {
    h = bf16_rne(x);
    l = bf16_rne(x - bf16_f(h));
}

// ---------- K1: u = q @ W (split-bf16; W staged+transposed+split in LDS)
//                + beta blocks (blockIdx.x >= 192) ----------
__global__ __launch_bounds__(256) void k_u_beta(const float* __restrict__ q,
    const float* __restrict__ W, const float* __restrict__ bias,
    unsigned short* __restrict__ uh, unsigned short* __restrict__ ul,
    float* __restrict__ beta)
{
    if (blockIdx.x >= 192) {
        const int row = (blockIdx.x - 192) * 4 + (threadIdx.x >> 6);
        const int lane = threadIdx.x & 63;
        float p = 0.f;
        for (int d = lane; d < H_; d += 64) p = fmaf(bias[d], q[(size_t)row * H_ + d], p);
#pragma unroll
        for (int o = 32; o; o >>= 1) p += __shfl_xor(p, o);
        if (lane == 0) beta[row] = p;
        return;
    }
    __shared__ unsigned short Wh[64][40], Wl[64][40];
    const int m0 = (blockIdx.x & 15) * 64, n0 = (blockIdx.x >> 4) * 64;
    const int t = threadIdx.x, w = t >> 6, lane = t & 63;
    const int fm = lane & 15, quad = lane >> 4;
    const int mrow = m0 + w * 16 + fm;
    const int dd = t >> 3, hc = (t & 7) * 8;
    f4v acc[4];
#pragma unroll
    for (int j = 0; j < 4; ++j) acc[j] = (f4v){0.f, 0.f, 0.f, 0.f};
    for (int k0 = 0; k0 < H_; k0 += 32) {
        const float* wp = &W[(size_t)(k0 + dd) * H_ + n0 + hc];
        const float4 v0 = *(const float4*)wp, v1 = *(const float4*)(wp + 4);
        const float* ap = &q[(size_t)mrow * H_ + k0 + quad * 8];
        const float4 a0 = *(const float4*)ap, a1 = *(const float4*)(ap + 4);
        const float as[8] = {a0.x, a0.y, a0.z, a0.w, a1.x, a1.y, a1.z, a1.w};
        s8v fah, fal;
#pragma unroll
        for (int j = 0; j < 8; ++j) { unsigned short h, l; split2(as[j], h, l); fah[j] = (short)h; fal[j] = (short)l; }
        const float ws[8] = {v0.x, v0.y, v0.z, v0.w, v1.x, v1.y, v1.z, v1.w};
        __syncthreads();   // protect previous iteration's LDS reads
#pragma unroll
        for (int j = 0; j < 8; ++j) {
            unsigned short h, l; split2(ws[j], h, l);
            Wh[hc + j][dd] = h; Wl[hc + j][dd] = l;
        }
        __syncthreads();
#pragma unroll
        for (int tn = 0; tn < 4; ++tn) {
            const s8v bh = *(const s8v*)&Wh[tn * 16 + fm][quad * 8];
            const s8v bl = *(const s8v*)&Wl[tn * 16 + fm][quad * 8];
            acc[tn] = __builtin_amdgcn_mfma_f32_16x16x32_bf16(fah, bh, acc[tn], 0, 0, 0);
            acc[tn] = __builtin_amdgcn_mfma_f32_16x16x32_bf16(fah, bl, acc[tn], 0, 0, 0);
            acc[tn] = __builtin_amdgcn_mfma_f32_16x16x32_bf16(fal, bh, acc[tn], 0, 0, 0);
        }
    }
#pragma unroll
    for (int tn = 0; tn < 4; ++tn) {
        const int col = n0 + tn * 16 + fm;
#pragma unroll
        for (int r = 0; r < 4; ++r) {
            const int row = m0 + w * 16 + quad * 4 + r;
            unsigned short h, l; split2(acc[tn][r], h, l);
            uh[(size_t)row * H_ + col] = h;
            ul[(size_t)row * H_ + col] = l;
        }
    }
}

// ---------- K2: s = c @ u^T + beta; 32-row tiles, 512 threads, BK=64.
//   8 waves: wave w -> msub=(w>>2)*16, ntile=(w&3)*16 (16x16 acc each).
//   Staging: 512 thr x float4 = 32x64 c-chunk per barrier (12 barriers).
//   Epilogue: row softmax -> s1, transposed raw s -> sT[b][q][c]. ----------
__global__ __launch_bounds__(512) void k_s_sm(const float* __restrict__ c,
    const unsigned short* __restrict__ uh, const unsigned short* __restrict__ ul,
    const float* __restrict__ beta, const int* __restrict__ q_mask,
    float* __restrict__ sT, unsigned short* __restrict__ s1)
{
    __shared__ unsigned short chh[2][32][72], cll[2][32][72];
    __shared__ float sL[32][65];
    const int m0 = blockIdx.x * 32;
    const int batch = m0 >> 9;
    const int cloc = m0 & (CL_ - 1);
    const int t = threadIdx.x, w = t >> 6, lane = t & 63;
    const int fm = lane & 15, quad = lane >> 4;
    const int msub = (w >> 2) * 16, ntile = (w & 3) * 16;
    const int srow = t >> 4, sc4 = (t & 15) * 4;   // staging: 32 rows x 64 k, 4 floats/thread
    f4v acc = (f4v){0.f, 0.f, 0.f, 0.f};

    const size_t urow = (size_t)(batch * QL_ + ntile + fm) * H_;

    float4 v = *(const float4*)&c[(size_t)(m0 + srow) * H_ + sc4];
    int p = 0;
    for (int k0 = 0; k0 < H_; k0 += 64) {
        ushort4 hh, ll;
        split2(v.x, hh.x, ll.x); split2(v.y, hh.y, ll.y);
        split2(v.z, hh.z, ll.z); split2(v.w, hh.w, ll.w);
        *(ushort4*)&chh[p][srow][sc4] = hh;
        *(ushort4*)&cll[p][srow][sc4] = ll;
        __syncthreads();
        if (k0 + 64 < H_) v = *(const float4*)&c[(size_t)(m0 + srow) * H_ + k0 + 64 + sc4];
#pragma unroll
        for (int kk = 0; kk < 2; ++kk) {
            const s8v fah = *(const s8v*)&chh[p][msub + fm][kk * 32 + quad * 8];
            const s8v fal = *(const s8v*)&cll[p][msub + fm][kk * 32 + quad * 8];
            const s8v bh = *(const s8v*)&uh[urow + k0 + kk * 32 + quad * 8];
            const s8v bl = *(const s8v*)&ul[urow + k0 + kk * 32 + quad * 8];
            acc = __builtin_amdgcn_mfma_f32_16x16x32_bf16(fah, bh, acc, 0, 0, 0);
            acc = __builtin_amdgcn_mfma_f32_16x16x32_bf16(fah, bl, acc, 0, 0, 0);
            acc = __builtin_amdgcn_mfma_f32_16x16x32_bf16(fal, bh, acc, 0, 0, 0);
        }
        p ^= 1;
    }
    // epilogue: fill sL tile (32 x 64)
    {
        const int col = ntile + fm;
        const float bb = beta[batch * QL_ + col];
#pragma unroll
        for (int r = 0; r < 4; ++r)
            sL[msub + quad * 4 + r][col] = acc[r] + bb;
    }
    __syncthreads();
    // row softmax over q (64 cols); wave w handles rows 4w..4w+3 of 32
    const bool qm = q_mask[batch * QL_ + lane] != 0;
#pragma unroll
    for (int rr = 0; rr < 4; ++rr) {
        const int lr = w * 4 + rr;
        const float x = qm ? sL[lr][lane] : -1e30f;
        float mx = x;
#pragma unroll
        for (int o = 32; o; o >>= 1) mx = fmaxf(mx, __shfl_xor(mx, o));
        const float e = __expf(x - mx);
        float sm = e;
#pragma unroll
        for (int o = 32; o; o >>= 1) sm += __shfl_xor(sm, o);
        s1[(size_t)(m0 + lr) * QL_ + lane] = bf16_rne(e / sm);
    }
    // transposed raw-s write: sT[b][q][cloc..cloc+31]
    {
        const int qq = t >> 3, c4o = (t & 7) * 4;
        float4 ov;
        ov.x = sL[c4o + 0][qq];
        ov.y = sL[c4o + 1][qq];
        ov.z = sL[c4o + 2][qq];
        ov.w = sL[c4o + 3][qq];
        *(float4*)&sT[((size_t)batch * QL_ + qq) * CL_ + cloc + c4o] = ov;
    }
}

// ---------- K3: fused colSM + t + finalize, 512 threads (8 waves), one block per (h0, b).
//   A) colSM from sT -> s2L (LDS bf16, XOR-swz), 8 q-rows per wave
//   B) stage qT
//   C) t-slice = s2^T @ c, K split across 2 wave-groups (own DB c-tiles),
//      partial accs merged via LDS
//   D) finalize all 512 c-rows, one 64-row chunk per wave ----------
__global__ __launch_bounds__(512) void k_tfin3(const float* __restrict__ sT,
    const unsigned short* __restrict__ s1, const float* __restrict__ q,
    const float* __restrict__ c, const int* __restrict__ c_mask,
    float* __restrict__ out)
{
    __shared__ unsigned short s2L[64 * 512];      // colSM result, XOR-swizzled (65536 B)
    __shared__ unsigned short Bs[2][2][64][40];   // c^T staging, [grp][dbuf]   (20480 B)
    __shared__ unsigned short qT[64][72];         // q^T bf16 (h x q)            (9216 B)
    __shared__ unsigned short tT[64][72];         // t   bf16 (h x q)            (9216 B)
    const int h0 = blockIdx.x * 64;
    const int b  = blockIdx.y;
    const int t = threadIdx.x, w = t >> 6, lane = t & 63;
    const int fm = lane & 15, quad = lane >> 4;
    const int grp = w >> 2;        // K-half: 0 -> d0 in [0,256), 1 -> [256,512)
    const int wl  = w & 3;         // h-partition within group (wl*16 .. wl*16+15)

    // ---- phase A: column softmax (over c) for batch b -> s2L (8 q-rows/wave) ----
    {
        const int cbase8 = lane * 8;
        int cm8[8];
#pragma unroll
        for (int j = 0; j < 8; ++j) cm8[j] = c_mask[b * CL_ + cbase8 + j];
        const float* stb = sT + (size_t)b * QL_ * CL_;
#pragma unroll
        for (int qi = 0; qi < 8; ++qi) {
            const int qq = w * 8 + qi;
            const float* sr = stb + (size_t)qq * CL_ + cbase8;
            const float4 v0 = *(const float4*)sr, v1 = *(const float4*)(sr + 4);
            float x[8] = {v0.x, v0.y, v0.z, v0.w, v1.x, v1.y, v1.z, v1.w};
#pragma unroll
            for (int j = 0; j < 8; ++j) x[j] = cm8[j] ? x[j] : -1e30f;
            float m = x[0];
#pragma unroll
            for (int j = 1; j < 8; ++j) m = fmaxf(m, x[j]);
#pragma unroll
            for (int o = 32; o; o >>= 1) m = fmaxf(m, __shfl_xor(m, o));
            float e[8], sm = 0.f;
#pragma unroll
            for (int j = 0; j < 8; ++j) { e[j] = __expf(x[j] - m); sm += e[j]; }
#pragma unroll
            for (int o = 32; o; o >>= 1) sm += __shfl_xor(sm, o);
            const float inv = 1.f / sm;
            s8v sv;
#pragma unroll
            for (int j = 0; j < 8; ++j) sv[j] = (short)bf16_rne(e[j] * inv);
            const int boff = ((qq * 512 + cbase8) * 2) ^ ((qq & 7) << 4);
            *(s8v*)((char*)s2L + boff) = sv;
        }
    }

    // ---- phase B: stage q^T (512 threads, 2 rows each) ----
    {
        const int r = t >> 4, c4 = (t & 15) * 4;
#pragma unroll
        for (int i = 0; i < 2; ++i) {
            const int qr = r + 32 * i;
            const float4 v = *(const float4*)&q[((size_t)b * QL_ + qr) * H_ + h0 + c4];
            qT[c4 + 0][qr] = bf16_rne(v.x);
            qT[c4 + 1][qr] = bf16_rne(v.y);
            qT[c4 + 2][qr] = bf16_rne(v.z);
            qT[c4 + 3][qr] = bf16_rne(v.w);
        }
    }

    // ---- phase C: t-slice = (s2^T @ c), K split across wave-groups ----
    f4v acc[4];
#pragma unroll
    for (int j = 0; j < 4; ++j) acc[j] = (f4v){0.f, 0.f, 0.f, 0.f};
    {
        const int tl = t & 255;                 // thread id within group
        const int dd = tl >> 3, hc = (tl & 7) * 8;
        const int gbase = grp * 256;            // this group's K offset
        const float* cp0 = &c[((size_t)b * CL_ + gbase + dd) * H_ + h0 + hc];
        float4 v0 = *(const float4*)cp0, v1 = *(const float4*)(cp0 + 4);
        int p = 0;
        for (int d0 = 0; d0 < 256; d0 += 32) {
            const float xs[8] = {v0.x, v0.y, v0.z, v0.w, v1.x, v1.y, v1.z, v1.w};
#pragma unroll
            for (int j = 0; j < 8; ++j) Bs[grp][p][hc + j][dd] = bf16_rne(xs[j]);
            __syncthreads();   // first iteration also orders phase-A/B LDS writes
            if (d0 + 32 < 256) {
                const float* cp = &c[((size_t)b * CL_ + gbase + d0 + 32 + dd) * H_ + h0 + hc];
                v0 = *(const float4*)cp; v1 = *(const float4*)(cp + 4);
            }
            const s8v fb = *(const s8v*)&Bs[grp][p][wl * 16 + fm][quad * 8];
#pragma unroll
            for (int tm = 0; tm < 4; ++tm) {
                const int boff = (((tm * 16 + fm) * 512 + gbase + d0 + quad * 8) * 2) ^ ((fm & 7) << 4);
                const s8v fa = *(const s8v*)((const char*)s2L + boff);
                acc[tm] = __builtin_amdgcn_mfma_f32_16x16x32_bf16(fa, fb, acc[tm], 0, 0, 0);
            }
            p ^= 1;
        }
    }
    __syncthreads();   // all s2L/Bs reads done before reusing s2L as dump area
    // merge group partials: grp1 dumps f32 accs into (dead) s2L, grp0 sums -> tT
    {
        float* dumpf = (float*)s2L;   // needs 16 KB of the 64 KB region
        if (grp == 1) {
#pragma unroll
            for (int tm = 0; tm < 4; ++tm)
#pragma unroll
                for (int r = 0; r < 4; ++r)
                    dumpf[((wl * 4 + tm) * 4 + r) * 64 + lane] = acc[tm][r];
        }
        __syncthreads();
        if (grp == 0) {
#pragma unroll
            for (int tm = 0; tm < 4; ++tm)
#pragma unroll
                for (int r = 0; r < 4; ++r)
                    tT[wl * 16 + fm][tm * 16 + quad * 4 + r] =
                        bf16_rne(acc[tm][r] + dumpf[((wl * 4 + tm) * 4 + r) * 64 + lane]);
        }
    }
    __syncthreads();

    // ---- phase D: finalize all 512 c-rows, one 64-row chunk per wave ----
    {
        const int cbase = w * 64;
        f4v aa[4][4], bb[4][4];
#pragma unroll
        for (int i = 0; i < 4; ++i)
#pragma unroll
            for (int j = 0; j < 4; ++j) { aa[i][j] = (f4v){0.f, 0.f, 0.f, 0.f}; bb[i][j] = aa[i][j]; }
#pragma unroll
        for (int ks = 0; ks < 2; ++ks) {
            s8v fa[4], fq[4], ft[4];
#pragma unroll
            for (int tm = 0; tm < 4; ++tm)
                fa[tm] = *(const s8v*)&s1[(size_t)(b * CL_ + cbase + tm * 16 + fm) * QL_ + ks * 32 + quad * 8];
#pragma unroll
            for (int tn = 0; tn < 4; ++tn) {
                fq[tn] = *(const s8v*)&qT[tn * 16 + fm][ks * 32 + quad * 8];
                ft[tn] = *(const s8v*)&tT[tn * 16 + fm][ks * 32 + quad * 8];
            }
#pragma unroll
            for (int tm = 0; tm < 4; ++tm)
#pragma unroll
                for (int tn = 0; tn < 4; ++tn) {
                    aa[tm][tn] = __builtin_amdgcn_mfma_f32_16x16x32_bf16(fa[tm], fq[tn], aa[tm][tn], 0, 0, 0);
                    bb[tm][tn] = __builtin_amdgcn_mfma_f32_16x16x32_bf16(fa[tm], ft[tn], bb[tm][tn], 0, 0, 0);
                }
        }
#pragma unroll
        for (int tm = 0; tm < 4; ++tm)
#pragma unroll
            for (int tn = 0; tn < 4; ++tn) {
                const int h = h0 + tn * 16 + fm;
#pragma unroll
                for (int r = 0; r < 4; ++r) {
                    const int crow = cbase + tm * 16 + quad * 4 + r;
                    const float cv = c[((size_t)b * CL_ + crow) * H_ + h];
                    const float av = aa[tm][tn][r], bv = bb[tm][tn][r];
                    float* ob = out + (size_t)(b * CL_ + crow) * (4 * H_);
                    ob[h]           = cv;
                    ob[H_ + h]      = av;
                    ob[2 * H_ + h]  = cv * av;
                    ob[3 * H_ + h]  = cv * bv;
                }
            }
    }
}

extern "C" void kernel_launch(void* const* d_in, const int* in_sizes, int n_in,
                              void* d_out, int out_size, void* d_ws, size_t ws_size,
                              hipStream_t stream) {
    const float* c      = (const float*)d_in[0];
    const float* q      = (const float*)d_in[1];
    const int*   c_mask = (const int*)d_in[2];
    const int*   q_mask = (const int*)d_in[3];
    const float* W      = (const float*)d_in[4];
    const float* bias   = (const float*)d_in[5];
    float* out = (float*)d_out;

    // workspace — total 6295552 B (~6.0 MB)
    char* base = (char*)d_ws;
    unsigned short* uh   = (unsigned short*)(base);               // 1572864
    unsigned short* ul   = (unsigned short*)(base + 1572864);     // 1572864
    float*          beta = (float*)(base + 3145728);              // 4096
    float*          sT   = (float*)(base + 3149824);              // 2097152 (f32 [16][64][512])
    unsigned short* s1   = (unsigned short*)(base + 5246976);     // 1048576

    k_u_beta <<<dim3(192 + 256), dim3(256), 0, stream>>>(q, W, bias, uh, ul, beta);
    k_s_sm   <<<dim3(256),       dim3(512), 0, stream>>>(c, uh, ul, beta, q_mask, sT, s1);
    k_tfin3  <<<dim3(12, 16),    dim3(512), 0, stream>>>(sT, s1, q, c, c_mask, out);
}

// Round 10
// 189.358 us; speedup vs baseline: 1.1309x; 1.0197x over previous
//
#include <hip/hip_runtime.h>
#include <math.h>

// BertBidafAttention B=16, CL=512, QL=64, H=768 — 3-launch pipeline.
// K2/K3: verified R9 versions (193.1 us). K1 change this round (mirror of the
// R9 K2 win): double-buffered Wh/Wl -> ONE barrier per 32-K step (24 vs 48),
// and next-tile W/q loads prefetched into regs before the MFMA cluster so HBM
// latency overlaps compute. MFMA order unchanged -> bit-identical numerics.
// K3 micro: first c-tile load hoisted to kernel entry (hides under phases A/B).

#define B_  16
#define CL_ 512
#define QL_ 64
#define H_  768
#define M_  (B_ * CL_)   // 8192

typedef __attribute__((ext_vector_type(8))) short s8v;   // 8 bf16
typedef __attribute__((ext_vector_type(4))) float f4v;   // MFMA acc

__device__ __forceinline__ unsigned short bf16_rne(float x) {
    unsigned int u = __float_as_uint(x);
    u += 0x7fffu + ((u >> 16) & 1u);
    return (unsigned short)(u >> 16);
}
__device__ __forceinline__ float bf16_f(unsigned short h) {
    return __uint_as_float((unsigned int)h << 16);
}
__device__ __forceinline__ void split2(float x, unsigned short& h, unsigned short& l) {
    h = bf16_rne(x);
    l = bf16_rne(x - bf16_f(h));
}

// ---------- K1: u = q @ W (split-bf16; W staged+transposed+split in DB LDS,
//                1 barrier/iter, reg-prefetched) + beta blocks (blockIdx.x >= 192) ----------
__global__ __launch_bounds__(256) void k_u_beta(const float* __restrict__ q,
    const float* __restrict__ W, const float* __restrict__ bias,
    unsigned short* __restrict__ uh, unsigned short* __restrict__ ul,
    float* __restrict__ beta)
{
    if (blockIdx.x >= 192) {
        const int row = (blockIdx.x - 192) * 4 + (threadIdx.x >> 6);
        const int lane = threadIdx.x & 63;
        float p = 0.f;
        for (int d = lane; d < H_; d += 64) p = fmaf(bias[d], q[(size_t)row * H_ + d], p);
#pragma unroll
        for (int o = 32; o; o >>= 1) p += __shfl_xor(p, o);
        if (lane == 0) beta[row] = p;
        return;
    }
    __shared__ unsigned short Wh[2][64][40], Wl[2][64][40];
    const int m0 = (blockIdx.x & 15) * 64, n0 = (blockIdx.x >> 4) * 64;
    const int t = threadIdx.x, w = t >> 6, lane = t & 63;
    const int fm = lane & 15, quad = lane >> 4;
    const int mrow = m0 + w * 16 + fm;
    const int dd = t >> 3, hc = (t & 7) * 8;
    f4v acc[4];
#pragma unroll
    for (int j = 0; j < 4; ++j) acc[j] = (f4v){0.f, 0.f, 0.f, 0.f};
    // preload tile 0 (W) and fragment 0 (q)
    const float* wp0 = &W[(size_t)dd * H_ + n0 + hc];
    float4 v0 = *(const float4*)wp0, v1 = *(const float4*)(wp0 + 4);
    const float* ap0 = &q[(size_t)mrow * H_ + quad * 8];
    float4 a0 = *(const float4*)ap0, a1 = *(const float4*)(ap0 + 4);
    int p = 0;
    for (int k0 = 0; k0 < H_; k0 += 32) {
        // split current regs into LDS (W) and frags (q)
        const float ws_[8] = {v0.x, v0.y, v0.z, v0.w, v1.x, v1.y, v1.z, v1.w};
#pragma unroll
        for (int j = 0; j < 8; ++j) {
            unsigned short h, l; split2(ws_[j], h, l);
            Wh[p][hc + j][dd] = h; Wl[p][hc + j][dd] = l;
        }
        const float as[8] = {a0.x, a0.y, a0.z, a0.w, a1.x, a1.y, a1.z, a1.w};
        s8v fah, fal;
#pragma unroll
        for (int j = 0; j < 8; ++j) { unsigned short h, l; split2(as[j], h, l); fah[j] = (short)h; fal[j] = (short)l; }
        __syncthreads();
        // prefetch next tile/fragment (overlaps the MFMA cluster below)
        if (k0 + 32 < H_) {
            const float* wp = &W[(size_t)(k0 + 32 + dd) * H_ + n0 + hc];
            v0 = *(const float4*)wp; v1 = *(const float4*)(wp + 4);
            const float* ap = &q[(size_t)mrow * H_ + k0 + 32 + quad * 8];
            a0 = *(const float4*)ap; a1 = *(const float4*)(ap + 4);
        }
#pragma unroll
        for (int tn = 0; tn < 4; ++tn) {
            const s8v bh = *(const s8v*)&Wh[p][tn * 16 + fm][quad * 8];
            const s8v bl = *(const s8v*)&Wl[p][tn * 16 + fm][quad * 8];
            acc[tn] = __builtin_amdgcn_mfma_f32_16x16x32_bf16(fah, bh, acc[tn], 0, 0, 0);
            acc[tn] = __builtin_amdgcn_mfma_f32_16x16x32_bf16(fah, bl, acc[tn], 0, 0, 0);
            acc[tn] = __builtin_amdgcn_mfma_f32_16x16x32_bf16(fal, bh, acc[tn], 0, 0, 0);
        }
        p ^= 1;
    }
#pragma unroll
    for (int tn = 0; tn < 4; ++tn) {
        const int col = n0 + tn * 16 + fm;
#pragma unroll
        for (int r = 0; r < 4; ++r) {
            const int row = m0 + w * 16 + quad * 4 + r;
            unsigned short h, l; split2(acc[tn][r], h, l);
            uh[(size_t)row * H_ + col] = h;
            ul[(size_t)row * H_ + col] = l;
        }
    }
}

// ---------- K2: s = c @ u^T + beta; 32-row tiles, 512 threads, BK=64.
//   8 waves: wave w -> msub=(w>>2)*16, ntile=(w&3)*16 (16x16 acc each).
//   Staging: 512 thr x float4 = 32x64 c-chunk per barrier (12 barriers).
//   Epilogue: row softmax -> s1, transposed raw s -> sT[b][q][c]. ----------
__global__ __launch_bounds__(512) void k_s_sm(const float* __restrict__ c,
    const unsigned short* __restrict__ uh, const unsigned short* __restrict__ ul,
    const float* __restrict__ beta, const int* __restrict__ q_mask,
    float* __restrict__ sT, unsigned short* __restrict__ s1)
{
    __shared__ unsigned short chh[2][32][72], cll[2][32][72];
    __shared__ float sL[32][65];
    const int m0 = blockIdx.x * 32;
    const int batch = m0 >> 9;
    const int cloc = m0 & (CL_ - 1);
    const int t = threadIdx.x, w = t >> 6, lane = t & 63;
    const int fm = lane & 15, quad = lane >> 4;
    const int msub = (w >> 2) * 16, ntile = (w & 3) * 16;
    const int srow = t >> 4, sc4 = (t & 15) * 4;   // staging: 32 rows x 64 k, 4 floats/thread
    f4v acc = (f4v){0.f, 0.f, 0.f, 0.f};

    const size_t urow = (size_t)(batch * QL_ + ntile + fm) * H_;

    float4 v = *(const float4*)&c[(size_t)(m0 + srow) * H_ + sc4];
    int p = 0;
    for (int k0 = 0; k0 < H_; k0 += 64) {
        ushort4 hh, ll;
        split2(v.x, hh.x, ll.x); split2(v.y, hh.y, ll.y);
        split2(v.z, hh.z, ll.z); split2(v.w, hh.w, ll.w);
        *(ushort4*)&chh[p][srow][sc4] = hh;
        *(ushort4*)&cll[p][srow][sc4] = ll;
        __syncthreads();
        if (k0 + 64 < H_) v = *(const float4*)&c[(size_t)(m0 + srow) * H_ + k0 + 64 + sc4];
#pragma unroll
        for (int kk = 0; kk < 2; ++kk) {
            const s8v fah = *(const s8v*)&chh[p][msub + fm][kk * 32 + quad * 8];
            const s8v fal = *(const s8v*)&cll[p][msub + fm][kk * 32 + quad * 8];
            const s8v bh = *(const s8v*)&uh[urow + k0 + kk * 32 + quad * 8];
            const s8v bl = *(const s8v*)&ul[urow + k0 + kk * 32 + quad * 8];
            acc = __builtin_amdgcn_mfma_f32_16x16x32_bf16(fah, bh, acc, 0, 0, 0);
            acc = __builtin_amdgcn_mfma_f32_16x16x32_bf16(fah, bl, acc, 0, 0, 0);
            acc = __builtin_amdgcn_mfma_f32_16x16x32_bf16(fal, bh, acc, 0, 0, 0);
        }
        p ^= 1;
    }
    // epilogue: fill sL tile (32 x 64)
    {
        const int col = ntile + fm;
        const float bb = beta[batch * QL_ + col];
#pragma unroll
        for (int r = 0; r < 4; ++r)
            sL[msub + quad * 4 + r][col] = acc[r] + bb;
    }
    __syncthreads();
    // row softmax over q (64 cols); wave w handles rows 4w..4w+3 of 32
    const bool qm = q_mask[batch * QL_ + lane] != 0;
#pragma unroll
    for (int rr = 0; rr < 4; ++rr) {
        const int lr = w * 4 + rr;
        const float x = qm ? sL[lr][lane] : -1e30f;
        float mx = x;
#pragma unroll
        for (int o = 32; o; o >>= 1) mx = fmaxf(mx, __shfl_xor(mx, o));
        const float e = __expf(x - mx);
        float sm = e;
#pragma unroll
        for (int o = 32; o; o >>= 1) sm += __shfl_xor(sm, o);
        s1[(size_t)(m0 + lr) * QL_ + lane] = bf16_rne(e / sm);
    }
    // transposed raw-s write: sT[b][q][cloc..cloc+31]
    {
        const int qq = t >> 3, c4o = (t & 7) * 4;
        float4 ov;
        ov.x = sL[c4o + 0][qq];
        ov.y = sL[c4o + 1][qq];
        ov.z = sL[c4o + 2][qq];
        ov.w = sL[c4o + 3][qq];
        *(float4*)&sT[((size_t)batch * QL_ + qq) * CL_ + cloc + c4o] = ov;
    }
}

// ---------- K3: fused colSM + t + finalize, 512 threads (8 waves), one block per (h0, b).
//   A) colSM from sT -> s2L (LDS bf16, XOR-swz), 8 q-rows per wave
//   B) stage qT
//   C) t-slice = s2^T @ c, K split across 2 wave-groups (own DB c-tiles),
//      partial accs merged via LDS  (first c-tile load hoisted to kernel entry)
//   D) finalize all 512 c-rows, one 64-row chunk per wave ----------
__global__ __launch_bounds__(512) void k_tfin3(const float* __restrict__ sT,
    const unsigned short* __restrict__ s1, const float* __restrict__ q,
    const float* __restrict__ c, const int* __restrict__ c_mask,
    float* __restrict__ out)
{
    __shared__ unsigned short s2L[64 * 512];      // colSM result, XOR-swizzled (65536 B)
    __shared__ unsigned short Bs[2][2][64][40];   // c^T staging, [grp][dbuf]   (20480 B)
    __shared__ unsigned short qT[64][72];         // q^T bf16 (h x q)            (9216 B)
    __shared__ unsigned short tT[64][72];         // t   bf16 (h x q)            (9216 B)
    const int h0 = blockIdx.x * 64;
    const int b  = blockIdx.y;
    const int t = threadIdx.x, w = t >> 6, lane = t & 63;
    const int fm = lane & 15, quad = lane >> 4;
    const int grp = w >> 2;        // K-half: 0 -> d0 in [0,256), 1 -> [256,512)
    const int wl  = w & 3;         // h-partition within group (wl*16 .. wl*16+15)

    // hoisted first c-tile load for phase C (in flight during phases A/B)
    const int tl = t & 255;                 // thread id within group
    const int cdd = tl >> 3, chc = (tl & 7) * 8;
    const int gbase = grp * 256;            // this group's K offset
    const float* cp0 = &c[((size_t)b * CL_ + gbase + cdd) * H_ + h0 + chc];
    float4 cv0 = *(const float4*)cp0, cv1 = *(const float4*)(cp0 + 4);

    // ---- phase A: column softmax (over c) for batch b -> s2L (8 q-rows/wave) ----
    {
        const int cbase8 = lane * 8;
        int cm8[8];
#pragma unroll
        for (int j = 0; j < 8; ++j) cm8[j] = c_mask[b * CL_ + cbase8 + j];
        const float* stb = sT + (size_t)b * QL_ * CL_;
#pragma unroll
        for (int qi = 0; qi < 8; ++qi) {
            const int qq = w * 8 + qi;
            const float* sr = stb + (size_t)qq * CL_ + cbase8;
            const float4 v0 = *(const float4*)sr, v1 = *(const float4*)(sr + 4);
            float x[8] = {v0.x, v0.y, v0.z, v0.w, v1.x, v1.y, v1.z, v1.w};
#pragma unroll
            for (int j = 0; j < 8; ++j) x[j] = cm8[j] ? x[j] : -1e30f;
            float m = x[0];
#pragma unroll
            for (int j = 1; j < 8; ++j) m = fmaxf(m, x[j]);
#pragma unroll
            for (int o = 32; o; o >>= 1) m = fmaxf(m, __shfl_xor(m, o));
            float e[8], sm = 0.f;
#pragma unroll
            for (int j = 0; j < 8; ++j) { e[j] = __expf(x[j] - m); sm += e[j]; }
#pragma unroll
            for (int o = 32; o; o >>= 1) sm += __shfl_xor(sm, o);
            const float inv = 1.f / sm;
            s8v sv;
#pragma unroll
            for (int j = 0; j < 8; ++j) sv[j] = (short)bf16_rne(e[j] * inv);
            const int boff = ((qq * 512 + cbase8) * 2) ^ ((qq & 7) << 4);
            *(s8v*)((char*)s2L + boff) = sv;
        }
    }

    // ---- phase B: stage q^T (512 threads, 2 rows each) ----
    {
        const int r = t >> 4, c4 = (t & 15) * 4;
#pragma unroll
        for (int i = 0; i < 2; ++i) {
            const int qr = r + 32 * i;
            const float4 v = *(const float4*)&q[((size_t)b * QL_ + qr) * H_ + h0 + c4];
            qT[c4 + 0][qr] = bf16_rne(v.x);
            qT[c4 + 1][qr] = bf16_rne(v.y);
            qT[c4 + 2][qr] = bf16_rne(v.z);
            qT[c4 + 3][qr] = bf16_rne(v.w);
        }
    }

    // ---- phase C: t-slice = (s2^T @ c), K split across wave-groups ----
    f4v acc[4];
#pragma unroll
    for (int j = 0; j < 4; ++j) acc[j] = (f4v){0.f, 0.f, 0.f, 0.f};
    {
        int p = 0;
        for (int d0 = 0; d0 < 256; d0 += 32) {
            const float xs[8] = {cv0.x, cv0.y, cv0.z, cv0.w, cv1.x, cv1.y, cv1.z, cv1.w};
#pragma unroll
            for (int j = 0; j < 8; ++j) Bs[grp][p][chc + j][cdd] = bf16_rne(xs[j]);
            __syncthreads();   // first iteration also orders phase-A/B LDS writes
            if (d0 + 32 < 256) {
                const float* cp = &c[((size_t)b * CL_ + gbase + d0 + 32 + cdd) * H_ + h0 + chc];
                cv0 = *(const float4*)cp; cv1 = *(const float4*)(cp + 4);
            }
            const s8v fb = *(const s8v*)&Bs[grp][p][wl * 16 + fm][quad * 8];
#pragma unroll
            for (int tm = 0; tm < 4; ++tm) {
                const int boff = (((tm * 16 + fm) * 512 + gbase + d0 + quad * 8) * 2) ^ ((fm & 7) << 4);
                const s8v fa = *(const s8v*)((const char*)s2L + boff);
                acc[tm] = __builtin_amdgcn_mfma_f32_16x16x32_bf16(fa, fb, acc[tm], 0, 0, 0);
            }
            p ^= 1;
        }
    }
    __syncthreads();   // all s2L/Bs reads done before reusing s2L as dump area
    // merge group partials: grp1 dumps f32 accs into (dead) s2L, grp0 sums -> tT
    {
        float* dumpf = (float*)s2L;   // needs 16 KB of the 64 KB region
        if (grp == 1) {
#pragma unroll
            for (int tm = 0; tm < 4; ++tm)
#pragma unroll
                for (int r = 0; r < 4; ++r)
                    dumpf[((wl * 4 + tm) * 4 + r) * 64 + lane] = acc[tm][r];
        }
        __syncthreads();
        if (grp == 0) {
#pragma unroll
            for (int tm = 0; tm < 4; ++tm)
#pragma unroll
                for (int r = 0; r < 4; ++r)
                    tT[wl * 16 + fm][tm * 16 + quad * 4 + r] =
                        bf16_rne(acc[tm][r] + dumpf[((wl * 4 + tm) * 4 + r) * 64 + lane]);
        }
    }
    __syncthreads();

    // ---- phase D: finalize all 512 c-rows, one 64-row chunk per wave ----
    {
        const int cbase = w * 64;
        f4v aa[4][4], bb[4][4];
#pragma unroll
        for (int i = 0; i < 4; ++i)
#pragma unroll
            for (int j = 0; j < 4; ++j) { aa[i][j] = (f4v){0.f, 0.f, 0.f, 0.f}; bb[i][j] = aa[i][j]; }
#pragma unroll
        for (int ks = 0; ks < 2; ++ks) {
            s8v fa[4], fq[4], ft[4];
#pragma unroll
            for (int tm = 0; tm < 4; ++tm)
                fa[tm] = *(const s8v*)&s1[(size_t)(b * CL_ + cbase + tm * 16 + fm) * QL_ + ks * 32 + quad * 8];
#pragma unroll
            for (int tn = 0; tn < 4; ++tn) {
                fq[tn] = *(const s8v*)&qT[tn * 16 + fm][ks * 32 + quad * 8];
                ft[tn] = *(const s8v*)&tT[tn * 16 + fm][ks * 32 + quad * 8];
            }
#pragma unroll
            for (int tm = 0; tm < 4; ++tm)
#pragma unroll
                for (int tn = 0; tn < 4; ++tn) {
                    aa[tm][tn] = __builtin_amdgcn_mfma_f32_16x16x32_bf16(fa[tm], fq[tn], aa[tm][tn], 0, 0, 0);
                    bb[tm][tn] = __builtin_amdgcn_mfma_f32_16x16x32_bf16(fa[tm], ft[tn], bb[tm][tn], 0, 0, 0);
                }
        }
#pragma unroll
        for (int tm = 0; tm < 4; ++tm)
#pragma unroll
            for (int tn = 0; tn < 4; ++tn) {
                const int h = h0 + tn * 16 + fm;
#pragma unroll
                for (int r = 0; r < 4; ++r) {
                    const int crow = cbase + tm * 16 + quad * 4 + r;
                    const float cv = c[((size_t)b * CL_ + crow) * H_ + h];
                    const float av = aa[tm][tn][r], bv = bb[tm][tn][r];
                    float* ob = out + (size_t)(b * CL_ + crow) * (4 * H_);
                    ob[h]           = cv;
                    ob[H_ + h]      = av;
                    ob[2 * H_ + h]  = cv * av;
                    ob[3 * H_ + h]  = cv * bv;
                }
            }
    }
}

extern "C" void kernel_launch(void* const* d_in, const int* in_sizes, int n_in,
                              void* d_out, int out_size, void* d_ws, size_t ws_size,
                              hipStream_t stream) {
    const float* c      = (const float*)d_in[0];
    const float* q      = (const float*)d_in[1];
    const int*   c_mask = (const int*)d_in[2];
    const int*   q_mask = (const int*)d_in[3];
    const float* W      = (const float*)d_in[4];
    const float* bias   = (const float*)d_in[5];
    float* out = (float*)d_out;

    // workspace — total 6295552 B (~6.0 MB)
    char* base = (char*)d_ws;
    unsigned short* uh   = (unsigned short*)(base);               // 1572864
    unsigned short* ul   = (unsigned short*)(base + 1572864);     // 1572864
    float*          beta = (float*)(base + 3145728);              // 4096
    float*          sT   = (float*)(base + 3149824);              // 2097152 (f32 [16][64][512])
    unsigned short* s1   = (unsigned short*)(base + 5246976);     // 1048576

    k_u_beta <<<dim3(192 + 256), dim3(256), 0, stream>>>(q, W, bias, uh, ul, beta);
    k_s_sm   <<<dim3(256),       dim3(512), 0, stream>>>(c, uh, ul, beta, q_mask, sT, s1);
    k_tfin3  <<<dim3(12, 16),    dim3(512), 0, stream>>>(sT, s1, q, c, c_mask, out);
}